// Round 11
// baseline (315.146 us; speedup 1.0000x reference)
//
#include <hip/hip_runtime.h>
#include <stdint.h>

// x: [4, 64, 128, 128, 10] f32, W: [10, 32, 64, 3,3,3] f32
// out: [4, 96, 128, 128, 10] f32 = cat([x, leaky_relu(conv)], axis=1)

typedef __bf16 bf16x8 __attribute__((ext_vector_type(8)));
typedef float f32x4 __attribute__((ext_vector_type(4)));
typedef unsigned short ushort_t;

__device__ __forceinline__ ushort_t f2bf(float f) {
    union { float f; uint32_t u; } v; v.f = f;
    uint32_t u = v.u;
    uint32_t r = (u + 0x7FFFu + ((u >> 16) & 1u)) >> 16;   // RNE
    return (ushort_t)r;
}

// ---------------- weights repack ----------------
// W[z,o,c,kd,kh,kw] f32 -> wt[(z*27+tap)*2048 + cg*256 + o*8 + ce] bf16
__global__ void prep_weights(const float* __restrict__ w, ushort_t* __restrict__ wt) {
    int t = blockIdx.x * 256 + threadIdx.x;
    if (t >= 552960) return;
    int ce  = t & 7;
    int o   = (t >> 3) & 31;
    int cg  = (t >> 8) & 7;
    int tap = (t >> 11) % 27;
    int z   = t / 55296;
    int c   = cg * 8 + ce;
    wt[t] = f2bf(w[((z * 32 + o) * 64 + c) * 27 + tap]);
}

// ======================= FAST PATH =======================
// xt layout: [b:4][d:128][hp:130][zp:12][c:64] bf16, zeros at hp in {0,129}, zp in {0,11}
#define XT_B  12779520   // 128*130*12*64
#define XT_D  99840      // 130*768
#define XT_H  768        // 12*64

__global__ void zero_hpads(ushort_t* __restrict__ xt) {
    int tid = threadIdx.x;
    if (tid >= 96) return;
    int bid = blockIdx.x;
    int e = bid & 1, d = (bid >> 1) & 127, b = bid >> 8;
    int hp = e ? 129 : 0;
    size_t u16off = ((size_t)(b * 128 + d) * 130 + hp) * 768;
    uint4 zz = {0u, 0u, 0u, 0u};
    ((uint4*)xt)[u16off / 8 + tid] = zz;
}

// fused: out[:, 0:64] = x  AND  repack x -> xt (bf16, transposed, z-padded).
__global__ __launch_bounds__(256) void repack_copy(
        const float* __restrict__ x, float* __restrict__ out, ushort_t* __restrict__ xt) {
    __shared__ __align__(16) ushort_t sm[16 * 12 * 64];

    int bid = blockIdx.x;
    int hc = bid & 7, d = (bid >> 3) & 127, b = bid >> 10;
    int h0 = hc * 16;
    int tid = threadIdx.x;
    int c = tid >> 2, q0 = tid & 3;

    {
        int hl = tid >> 4, rest = tid & 15;
        int zp = (rest >> 3) ? 11 : 0, s = rest & 7;
        uint4 zz = {0u, 0u, 0u, 0u};
        *(uint4*)&sm[hl * 768 + zp * 64 + s * 8] = zz;
    }

    const float4* s4 = (const float4*)(x   + ((size_t)(b * 64 + c) * 128 + d) * 1280 + h0 * 10);
    float4*       d4 = (float4*)      (out + ((size_t)(b * 96 + c) * 128 + d) * 1280 + h0 * 10);

    #pragma unroll
    for (int i = 0; i < 10; ++i) {
        int j = q0 + 4 * i;
        float4 v = s4[j];
        d4[j] = v;
        int p = 4 * j;
        int hl = (p * 52429) >> 19;
        int zz = p - 10 * hl;
        int addr = hl * 768 + (zz + 1) * 64 + c;
        float vv[4] = {v.x, v.y, v.z, v.w};
        #pragma unroll
        for (int k = 0; k < 4; ++k) {
            sm[addr] = f2bf(vv[k]);
            zz++;
            if (zz == 10) { zz = 0; addr += 192; } else addr += 64;
        }
    }
    __syncthreads();

    uint4* dx = (uint4*)(xt + ((size_t)(b * 128 + d) * 130 + h0 + 1) * 768);
    const uint4* sv = (const uint4*)sm;
    #pragma unroll
    for (int i = 0; i < 6; ++i) dx[tid + 256 * i] = sv[tid + 256 * i];
}

// conv v11: h64 tiles with (zh, od) wave split -> 4 MFMAs per JIT B-frag,
// half the total B L2-traffic of v9. acc[4][5] = 80 AGPR, VGPR ~55 -> ~135
// unified regs, 3 waves/SIMD = LDS limit (3 blocks x 4 waves). v7-proven
// staging (soff[13], wave-uniform dst) + padded coalesced epilogue.
// grid 1024 = (b, d, ht0..1). Wave: 64h (m=4) x 16o x 5z.
typedef __attribute__((address_space(3))) uint32_t lds_w;
typedef const __attribute__((address_space(1))) uint32_t glb_w;

__global__ __launch_bounds__(256, 3) void conv_v11(
        const ushort_t* __restrict__ xt, const ushort_t* __restrict__ wt,
        float* __restrict__ out) {
    __shared__ __align__(16) uint4 SL[3328];   // 13*256 granules x 16B = 53248 B (rows 0..69; 66..69 pad)

    int bid = blockIdx.x;
    int swz = ((bid & 7) << 7) | (bid >> 3);   // XCD-chunked, bijective (1024 % 8 == 0)
    int ht = swz & 1, d = (swz >> 1) & 127, b = swz >> 8;
    int h0 = ht << 6;

    int tid = threadIdx.x;
    int l = tid & 63, w = tid >> 6;
    int zh = w & 1, od = w >> 1;     // wave = (z-half, o-half)
    int lr = l & 15, lk = l >> 4;

    f32x4 acc[4][5];
    #pragma unroll
    for (int m = 0; m < 4; ++m)
        #pragma unroll
        for (int zl = 0; zl < 5; ++zl)
            acc[m][zl] = (f32x4){0.f, 0.f, 0.f, 0.f};

    const ushort_t* xb = xt + (size_t)b * XT_B;
    // lane's B base: o = od*16+lr -> od*128 + lr*8 ; cg = cc*4+lk -> lk*256 (+cc*1024 later)
    // plus wave-z base (zh*5)*27*2048
    const ushort_t* wb = wt + (size_t)(od * 128 + lr * 8 + lk * 256) + (size_t)zh * 5 * 27 * 2048;

    // per-thread swizzled stage source offsets (halfs), fixed across slabs:
    // granule s = i*256+tid -> row = s/48, gp = s%48, g = (gp - 5*(row&7)) mod 48
    int soff[13];
    #pragma unroll
    for (int i = 0; i < 13; ++i) {
        int s = i * 256 + tid;                                      // 0..3327
        int row = (int)(((unsigned)s * 43691u) >> 21);              // s / 48
        int gp = s - row * 48;
        int g = gp - 5 * (row & 7);
        if (g < 0) g += 48;
        int hp = h0 + row;
        if (hp > 129) hp = 129;                                     // pad rows 66..69, never read
        soff[i] = hp * 768 + (g >> 2) * 64 + (g & 3) * 8;
    }

    uint4* dst0 = SL + (size_t)w * 64;         // wave-uniform LDS base (proven form)

    for (int sidx = 0; sidx < 6; ++sidx) {
        int cc = (sidx >= 3) ? 1 : 0;
        int kd = sidx - 3 * cc;
        int dg = d - 1 + kd;
        if (dg < 0 || dg > 127) continue;          // block-uniform

        __syncthreads();                           // previous slab fully consumed
        // ---- stage: 13 full-exec gload_lds x 16B, wave-uniform dst ----
        const ushort_t* sb = xb + (size_t)dg * XT_D + cc * 32;
        #pragma unroll
        for (int i = 0; i < 13; ++i)
            __builtin_amdgcn_global_load_lds((glb_w*)(sb + soff[i]),
                                             (lds_w*)(dst0 + i * 256), 16, 0, 0);
        asm volatile("s_waitcnt vmcnt(0)" ::: "memory");
        __syncthreads();                           // slab visible to all waves

        // slab-local weight base: + kd*9 taps (+cc half of cg)
        const ushort_t* wk = wb + (size_t)kd * 9 * 2048 + cc * 1024;

        // ---- compute: 3 kh x 7 u, JIT B-frags; each frag feeds 4 MFMAs ----
        #pragma unroll
        for (int kh = 0; kh < 3; ++kh) {
            const int rowb = lr + kh;
            const int rot = 5 * (rowb & 7);
            #pragma unroll
            for (int u = 0; u < 7; ++u) {
                int g0 = 20 * zh + 4 * u + lk + rot;
                int gp2 = (g0 >= 48) ? g0 - 48 : g0;               // g0 < 96 -> one subtract
                const ushort_t* ap = (const ushort_t*)SL + (size_t)rowb * 384 + gp2 * 8;
                bf16x8 a[4];
                #pragma unroll
                for (int m = 0; m < 4; ++m)
                    a[m] = *(const bf16x8*)(ap + (size_t)m * 6144);   // +16 rows * 384 each
                #pragma unroll
                for (int kw = 0; kw < 3; ++kw) {
                    int zl = u - kw;
                    if (zl < 0 || zl > 4) continue;                // compile-time
                    bf16x8 bbf = *(const bf16x8*)&wk[(size_t)(zl * 27 + kh * 3 + kw) * 2048];
                    #pragma unroll
                    for (int m = 0; m < 4; ++m)
                        acc[m][zl] = __builtin_amdgcn_mfma_f32_16x16x32_bf16(
                            a[m], bbf, acc[m][zl], 0, 0, 0);
                }
            }
        }
    }

    // ---- epilogue: leaky-relu -> LDS transpose (two od rounds) -> coalesced stores ----
    // C/D: col(o)=lane&15, row(h-in-16-tile)=lk*4+r.  T[16][644] f32 (644%4==0 -> f4-aligned).
    float* T = (float*)SL;
    float* gb = out + (size_t)b * 15728640 + (size_t)64 * 163840 + (size_t)d * 1280 + h0 * 10;
    #pragma unroll
    for (int rd = 0; rd < 2; ++rd) {
        __syncthreads();                           // SL free (slab reads / prev round done)
        if (od == rd) {
            #pragma unroll
            for (int m = 0; m < 4; ++m)
                #pragma unroll
                for (int r = 0; r < 4; ++r) {
                    int hl = m * 16 + lk * 4 + r;
                    float* tp = T + lr * 644 + hl * 10 + zh * 5;
                    #pragma unroll
                    for (int zl = 0; zl < 5; ++zl) {
                        float v = acc[m][zl][r];
                        tp[zl] = (v >= 0.f) ? v : 0.2f * v;
                    }
                }
        }
        __syncthreads();
        const float4* Tv = (const float4*)T;
        #pragma unroll
        for (int i = 0; i < 10; ++i) {
            int idx = i * 256 + tid;               // 0..2559
            int o = (int)(((unsigned)idx * 52429u) >> 23);   // idx / 160
            int j4 = idx - o * 160;                // float4 within 640-float run
            *(float4*)(gb + (size_t)(rd * 16 + o) * 163840 + j4 * 4) = Tv[o * 161 + j4];
        }
    }
}

// ======================= FALLBACK PATH (R1) =======================
__global__ void copy_x(const float4* __restrict__ x, float4* __restrict__ out) {
    const int n = 10485760;
    for (int i = blockIdx.x * blockDim.x + threadIdx.x; i < n; i += gridDim.x * blockDim.x) {
        int b = i / 2621440;
        int rem = i - b * 2621440;
        out[b * 3932160 + rem] = x[i];
    }
}

#define RS 392
__global__ __launch_bounds__(256, 2) void conv_lc3d_v1(
        const float* __restrict__ x, const ushort_t* __restrict__ wt,
        float* __restrict__ out) {
    __shared__ __align__(16) ushort_t xls[66 * RS];
    const int bid = blockIdx.x;
    const int ht = bid & 1;
    const int d  = (bid >> 1) & 127;
    const int b  = bid >> 8;
    const int h0 = ht * 64;
    const int tid = threadIdx.x;
    const int l  = tid & 63;
    const int w  = tid >> 6;
    const int zh = w >> 1;
    const int mp = w & 1;
    const int lr = l & 15;
    const int lk = l >> 4;

    f32x4 acc[2][5][2];
    #pragma unroll
    for (int m = 0; m < 2; ++m)
        #pragma unroll
        for (int zl = 0; zl < 5; ++zl)
            #pragma unroll
            for (int oh = 0; oh < 2; ++oh)
                acc[m][zl][oh] = (f32x4){0.f, 0.f, 0.f, 0.f};

    for (int i = tid; i < 66 * 32; i += 256) {
        int hh = i >> 5, cl = i & 31;
        xls[hh * RS + cl] = 0;
        xls[hh * RS + 11 * 32 + cl] = 0;
    }
    const float* xb = x + (size_t)b * 10485760;
    for (int cc = 0; cc < 2; ++cc) {
        for (int kd = 0; kd < 3; ++kd) {
            const int dg = d - 1 + kd;
            const bool dgv = (dg >= 0) && (dg < 128);
            __syncthreads();
            for (int cl = w; cl < 32; cl += 4) {
                const float* src = xb + (size_t)(cc * 32 + cl) * 163840 + (size_t)dg * 1280 + (h0 - 1) * 10;
                for (int j = l; j < 660; j += 64) {
                    int hh = j / 10;
                    int zz = j - hh * 10 + 1;
                    int hg = h0 - 1 + hh;
                    float v = 0.f;
                    if (dgv && hg >= 0 && hg < 128) v = src[j];
                    xls[hh * RS + zz * 32 + cl] = f2bf(v);
                }
            }
            __syncthreads();
            #pragma unroll
            for (int kh = 0; kh < 3; ++kh) {
                #pragma unroll
                for (int u = 0; u < 7; ++u) {
                    const int zp = zh * 5 + u;
                    const bf16x8 a0 = *(const bf16x8*)&xls[(mp * 32 + lr + kh) * RS + zp * 32 + lk * 8];
                    const bf16x8 a1 = *(const bf16x8*)&xls[(mp * 32 + 16 + lr + kh) * RS + zp * 32 + lk * 8];
                    #pragma unroll
                    for (int kw = 0; kw < 3; ++kw) {
                        const int zl = u - kw;
                        if (zl < 0 || zl >= 5) continue;
                        const int z = zh * 5 + zl;
                        const int tap = kd * 9 + kh * 3 + kw;
                        #pragma unroll
                        for (int oh = 0; oh < 2; ++oh) {
                            const bf16x8 bf = *(const bf16x8*)&wt[
                                (size_t)(((z * 27 + tap) * 8 + cc * 4 + lk) * 32 + oh * 16 + lr) * 8];
                            acc[0][zl][oh] = __builtin_amdgcn_mfma_f32_16x16x32_bf16(a0, bf, acc[0][zl][oh], 0, 0, 0);
                            acc[1][zl][oh] = __builtin_amdgcn_mfma_f32_16x16x32_bf16(a1, bf, acc[1][zl][oh], 0, 0, 0);
                        }
                    }
                }
            }
        }
    }
    float* ob = out + (size_t)b * 15728640 + (size_t)d * 1280;
    #pragma unroll
    for (int m = 0; m < 2; ++m)
        #pragma unroll
        for (int zl = 0; zl < 5; ++zl)
            #pragma unroll
            for (int oh = 0; oh < 2; ++oh) {
                const int z = zh * 5 + zl;
                const int o = oh * 16 + lr;
                const int hl = (mp * 2 + m) * 16 + lk * 4;
                float* p = ob + (size_t)(64 + o) * 163840 + (h0 + hl) * 10 + z;
                #pragma unroll
                for (int r = 0; r < 4; ++r) {
                    float v = acc[m][zl][oh][r];
                    v = (v >= 0.f) ? v : 0.2f * v;
                    p[r * 10] = v;
                }
            }
}

// =============================== launch ===============================
extern "C" void kernel_launch(void* const* d_in, const int* in_sizes, int n_in,
                              void* d_out, int out_size, void* d_ws, size_t ws_size,
                              hipStream_t stream) {
    const float* x   = (const float*)d_in[0];
    const float* wts = (const float*)d_in[1];
    float* out = (float*)d_out;
    ushort_t* wt = (ushort_t*)d_ws;

    const size_t XT_OFF = 2u << 20;
    const size_t NEED = XT_OFF + (size_t)4 * XT_B * 2;

    prep_weights<<<2160, 256, 0, stream>>>(wts, wt);

    if (ws_size >= NEED) {
        ushort_t* xtp = (ushort_t*)((char*)d_ws + XT_OFF);
        zero_hpads<<<1024, 128, 0, stream>>>(xtp);
        repack_copy<<<4096, 256, 0, stream>>>(x, out, xtp);
        conv_v11<<<1024, 256, 0, stream>>>(xtp, wt, out);
    } else {
        copy_x<<<2048, 256, 0, stream>>>((const float4*)x, (float4*)out);
        conv_lc3d_v1<<<4 * 128 * 2, 256, 0, stream>>>(x, wt, out);
    }
}

// Round 12
// 241.185 us; speedup vs baseline: 1.3067x; 1.3067x over previous
//
#include <hip/hip_runtime.h>
#include <stdint.h>

// x: [4, 64, 128, 128, 10] f32, W: [10, 32, 64, 3,3,3] f32
// out: [4, 96, 128, 128, 10] f32 = cat([x, leaky_relu(conv)], axis=1)

typedef __bf16 bf16x8 __attribute__((ext_vector_type(8)));
typedef float f32x4 __attribute__((ext_vector_type(4)));
typedef unsigned short ushort_t;

__device__ __forceinline__ ushort_t f2bf(float f) {
    union { float f; uint32_t u; } v; v.f = f;
    uint32_t u = v.u;
    uint32_t r = (u + 0x7FFFu + ((u >> 16) & 1u)) >> 16;   // RNE
    return (ushort_t)r;
}

// ---------------- weights repack ----------------
// W[z,o,c,kd,kh,kw] f32 -> wt[(z*27+tap)*2048 + cg*256 + o*8 + ce] bf16
__global__ void prep_weights(const float* __restrict__ w, ushort_t* __restrict__ wt) {
    int t = blockIdx.x * 256 + threadIdx.x;
    if (t >= 552960) return;
    int ce  = t & 7;
    int o   = (t >> 3) & 31;
    int cg  = (t >> 8) & 7;
    int tap = (t >> 11) % 27;
    int z   = t / 55296;
    int c   = cg * 8 + ce;
    wt[t] = f2bf(w[((z * 32 + o) * 64 + c) * 27 + tap]);
}

// ======================= FAST PATH =======================
// xt layout: [b:4][d:128][hp:130][zp:12][c:64] bf16, zeros at hp in {0,129}, zp in {0,11}
#define XT_B  12779520   // 128*130*12*64
#define XT_D  99840      // 130*768
#define XT_H  768        // 12*64

__global__ void zero_hpads(ushort_t* __restrict__ xt) {
    int tid = threadIdx.x;
    if (tid >= 96) return;
    int bid = blockIdx.x;
    int e = bid & 1, d = (bid >> 1) & 127, b = bid >> 8;
    int hp = e ? 129 : 0;
    size_t u16off = ((size_t)(b * 128 + d) * 130 + hp) * 768;
    uint4 zz = {0u, 0u, 0u, 0u};
    ((uint4*)xt)[u16off / 8 + tid] = zz;
}

// fused: out[:, 0:64] = x  AND  repack x -> xt (bf16, transposed, z-padded).
__global__ __launch_bounds__(256) void repack_copy(
        const float* __restrict__ x, float* __restrict__ out, ushort_t* __restrict__ xt) {
    __shared__ __align__(16) ushort_t sm[16 * 12 * 64];

    int bid = blockIdx.x;
    int hc = bid & 7, d = (bid >> 3) & 127, b = bid >> 10;
    int h0 = hc * 16;
    int tid = threadIdx.x;
    int c = tid >> 2, q0 = tid & 3;

    {
        int hl = tid >> 4, rest = tid & 15;
        int zp = (rest >> 3) ? 11 : 0, s = rest & 7;
        uint4 zz = {0u, 0u, 0u, 0u};
        *(uint4*)&sm[hl * 768 + zp * 64 + s * 8] = zz;
    }

    const float4* s4 = (const float4*)(x   + ((size_t)(b * 64 + c) * 128 + d) * 1280 + h0 * 10);
    float4*       d4 = (float4*)      (out + ((size_t)(b * 96 + c) * 128 + d) * 1280 + h0 * 10);

    #pragma unroll
    for (int i = 0; i < 10; ++i) {
        int j = q0 + 4 * i;
        float4 v = s4[j];
        d4[j] = v;
        int p = 4 * j;
        int hl = (p * 52429) >> 19;
        int zz = p - 10 * hl;
        int addr = hl * 768 + (zz + 1) * 64 + c;
        float vv[4] = {v.x, v.y, v.z, v.w};
        #pragma unroll
        for (int k = 0; k < 4; ++k) {
            sm[addr] = f2bf(vv[k]);
            zz++;
            if (zz == 10) { zz = 0; addr += 192; } else addr += 64;
        }
    }
    __syncthreads();

    uint4* dx = (uint4*)(xt + ((size_t)(b * 128 + d) * 130 + h0 + 1) * 768);
    const uint4* sv = (const uint4*)sm;
    #pragma unroll
    for (int i = 0; i < 6; ++i) dx[tid + 256 * i] = sv[tid + 256 * i];
}

// conv v12: v9 geometry (h32, (zh,od) waves, acc[2][5]=40 AGPR) +
//  (a) scalar-base B addressing: uniform pointer chain -> SALU adds, lane
//      offset applied only at the load (cuts ~90 VALU ops/slab), and
//  (b) depth-1 B prefetch: bb[2][3] parity rotation in the unrolled u-loop
//      (+24 VGPR, total ~128 unified regs -> still 4 waves/SIMD).
// grid 2048 = (b, d, ht0..3), 256 thr / 4 waves. Slab 28.6 KB.
typedef __attribute__((address_space(3))) uint32_t lds_w;
typedef const __attribute__((address_space(1))) uint32_t glb_w;

__global__ __launch_bounds__(256, 4) void conv_v12(
        const ushort_t* __restrict__ xt, const ushort_t* __restrict__ wt,
        float* __restrict__ out) {
    __shared__ __align__(16) uint4 SL[1792];   // 7*256 granules x 16B = 28672 B (rows 0..37; 34..37 pad)

    int bid = blockIdx.x;
    int swz = ((bid & 7) << 8) | (bid >> 3);   // XCD-chunked, bijective (2048 % 8 == 0)
    int ht = swz & 3, d = (swz >> 2) & 127, b = swz >> 9;
    int h0 = ht << 5;

    int tid = threadIdx.x;
    int l = tid & 63, w = tid >> 6;
    int zh = w & 1, od = w >> 1;     // wave = (z-half, o-half)
    int lr = l & 15, lk = l >> 4;

    f32x4 acc[2][5];
    #pragma unroll
    for (int m = 0; m < 2; ++m)
        #pragma unroll
        for (int zl = 0; zl < 5; ++zl)
            acc[m][zl] = (f32x4){0.f, 0.f, 0.f, 0.f};

    const ushort_t* xb = xt + (size_t)b * XT_B;
    const int wlo = od * 128 + lr * 8 + lk * 256;   // per-lane B offset (halfs) — applied at load only

    // per-thread swizzled stage source offsets (halfs), fixed across slabs:
    // granule s = i*256+tid -> row = s/48, gp = s%48, g = (gp - 5*(row&7)) mod 48
    int soff[7];
    #pragma unroll
    for (int i = 0; i < 7; ++i) {
        int s = i * 256 + tid;                                      // 0..1791
        int row = (int)(((unsigned)s * 43691u) >> 21);              // s / 48
        int gp = s - row * 48;
        int g = gp - 5 * (row & 7);
        if (g < 0) g += 48;
        int hp = h0 + row;
        if (hp > 129) hp = 129;                                     // pad rows 34..37, never read
        soff[i] = hp * 768 + (g >> 2) * 64 + (g & 3) * 8;
    }

    uint4* dst0 = SL + (size_t)w * 64;         // wave-uniform LDS base (proven form)

    for (int sidx = 0; sidx < 6; ++sidx) {
        int cc = (sidx >= 3) ? 1 : 0;
        int kd = sidx - 3 * cc;
        int dg = d - 1 + kd;
        if (dg < 0 || dg > 127) continue;          // block-uniform

        __syncthreads();                           // previous slab fully consumed
        // ---- stage: 7 full-exec gload_lds x 16B, wave-uniform dst ----
        const ushort_t* sb = xb + (size_t)dg * XT_D + cc * 32;
        #pragma unroll
        for (int i = 0; i < 7; ++i)
            __builtin_amdgcn_global_load_lds((glb_w*)(sb + soff[i]),
                                             (lds_w*)(dst0 + i * 256), 16, 0, 0);
        asm volatile("s_waitcnt vmcnt(0)" ::: "memory");
        __syncthreads();                           // slab visible to all waves

        // uniform slab weight base (zh is wave-uniform; kept out of lane pointer)
        const ushort_t* wzs = wt + (size_t)zh * 5 * 27 * 2048
                                 + (size_t)kd * 9 * 2048 + (size_t)cc * 1024;

        // ---- compute: 3 kh x 7 u; depth-1 B prefetch, scalar-base loads ----
        #pragma unroll
        for (int kh = 0; kh < 3; ++kh) {
            const ushort_t* wku = wzs + (size_t)kh * 3 * 2048;   // uniform
            const int rowb = lr + kh;
            const int rot = 5 * (rowb & 7);

            bf16x8 bb[2][3];
            auto loadB = [&](int u, int pi) {
                #pragma unroll
                for (int kw = 0; kw < 3; ++kw) {
                    int zl = u - kw;
                    if (zl >= 0 && zl <= 4) {
                        const ushort_t* wp = wku + (size_t)(zl * 27 + kw) * 2048;  // uniform
                        bb[pi][kw] = *(const bf16x8*)&wp[wlo];                      // lane offset here
                    }
                }
            };
            auto doMfma = [&](int u, int pi) {
                int g0 = 20 * zh + 4 * u + lk + rot;
                int gp2 = (g0 >= 48) ? g0 - 48 : g0;
                const ushort_t* ap = (const ushort_t*)SL + (size_t)rowb * 384 + gp2 * 8;
                bf16x8 a0 = *(const bf16x8*)ap;
                bf16x8 a1 = *(const bf16x8*)(ap + 6144);           // +16 rows * 384
                #pragma unroll
                for (int kw = 0; kw < 3; ++kw) {
                    int zl = u - kw;
                    if (zl >= 0 && zl <= 4) {
                        acc[0][zl] = __builtin_amdgcn_mfma_f32_16x16x32_bf16(a0, bb[pi][kw], acc[0][zl], 0, 0, 0);
                        acc[1][zl] = __builtin_amdgcn_mfma_f32_16x16x32_bf16(a1, bb[pi][kw], acc[1][zl], 0, 0, 0);
                    }
                }
            };

            loadB(0, 0);
            #pragma unroll
            for (int u = 0; u < 7; ++u) {
                if (u < 6) loadB(u + 1, (u + 1) & 1);   // prefetch next-u frags
                doMfma(u, u & 1);                        // indices static post-unroll
            }
        }
    }

    // ---- epilogue: leaky-relu -> LDS transpose (two od rounds) -> coalesced stores ----
    // C/D: col(o)=lane&15, row(h-in-16-tile)=lk*4+r.  T[16][324] f32 (324%4==0 -> f4-aligned).
    float* T = (float*)SL;
    float* gb = out + (size_t)b * 15728640 + (size_t)64 * 163840 + (size_t)d * 1280 + h0 * 10;
    #pragma unroll
    for (int rd = 0; rd < 2; ++rd) {
        __syncthreads();                           // SL free (slab reads / prev round done)
        if (od == rd) {
            #pragma unroll
            for (int m = 0; m < 2; ++m)
                #pragma unroll
                for (int r = 0; r < 4; ++r) {
                    int hl = m * 16 + lk * 4 + r;
                    float* tp = T + lr * 324 + hl * 10 + zh * 5;
                    #pragma unroll
                    for (int zl = 0; zl < 5; ++zl) {
                        float v = acc[m][zl][r];
                        tp[zl] = (v >= 0.f) ? v : 0.2f * v;
                    }
                }
        }
        __syncthreads();
        const float4* Tv = (const float4*)T;
        #pragma unroll
        for (int i = 0; i < 5; ++i) {
            int idx = i * 256 + tid;               // 0..1279
            int o = idx / 80;                      // o-local 0..15 (compiler magic-div)
            int j4 = idx - o * 80;                 // float4 within 320-float run
            *(float4*)(gb + (size_t)(rd * 16 + o) * 163840 + j4 * 4) = Tv[o * 81 + j4];
        }
    }
}

// ======================= FALLBACK PATH (R1) =======================
__global__ void copy_x(const float4* __restrict__ x, float4* __restrict__ out) {
    const int n = 10485760;
    for (int i = blockIdx.x * blockDim.x + threadIdx.x; i < n; i += gridDim.x * blockDim.x) {
        int b = i / 2621440;
        int rem = i - b * 2621440;
        out[b * 3932160 + rem] = x[i];
    }
}

#define RS 392
__global__ __launch_bounds__(256, 2) void conv_lc3d_v1(
        const float* __restrict__ x, const ushort_t* __restrict__ wt,
        float* __restrict__ out) {
    __shared__ __align__(16) ushort_t xls[66 * RS];
    const int bid = blockIdx.x;
    const int ht = bid & 1;
    const int d  = (bid >> 1) & 127;
    const int b  = bid >> 8;
    const int h0 = ht * 64;
    const int tid = threadIdx.x;
    const int l  = tid & 63;
    const int w  = tid >> 6;
    const int zh = w >> 1;
    const int mp = w & 1;
    const int lr = l & 15;
    const int lk = l >> 4;

    f32x4 acc[2][5][2];
    #pragma unroll
    for (int m = 0; m < 2; ++m)
        #pragma unroll
        for (int zl = 0; zl < 5; ++zl)
            #pragma unroll
            for (int oh = 0; oh < 2; ++oh)
                acc[m][zl][oh] = (f32x4){0.f, 0.f, 0.f, 0.f};

    for (int i = tid; i < 66 * 32; i += 256) {
        int hh = i >> 5, cl = i & 31;
        xls[hh * RS + cl] = 0;
        xls[hh * RS + 11 * 32 + cl] = 0;
    }
    const float* xb = x + (size_t)b * 10485760;
    for (int cc = 0; cc < 2; ++cc) {
        for (int kd = 0; kd < 3; ++kd) {
            const int dg = d - 1 + kd;
            const bool dgv = (dg >= 0) && (dg < 128);
            __syncthreads();
            for (int cl = w; cl < 32; cl += 4) {
                const float* src = xb + (size_t)(cc * 32 + cl) * 163840 + (size_t)dg * 1280 + (h0 - 1) * 10;
                for (int j = l; j < 660; j += 64) {
                    int hh = j / 10;
                    int zz = j - hh * 10 + 1;
                    int hg = h0 - 1 + hh;
                    float v = 0.f;
                    if (dgv && hg >= 0 && hg < 128) v = src[j];
                    xls[hh * RS + zz * 32 + cl] = f2bf(v);
                }
            }
            __syncthreads();
            #pragma unroll
            for (int kh = 0; kh < 3; ++kh) {
                #pragma unroll
                for (int u = 0; u < 7; ++u) {
                    const int zp = zh * 5 + u;
                    const bf16x8 a0 = *(const bf16x8*)&xls[(mp * 32 + lr + kh) * RS + zp * 32 + lk * 8];
                    const bf16x8 a1 = *(const bf16x8*)&xls[(mp * 32 + 16 + lr + kh) * RS + zp * 32 + lk * 8];
                    #pragma unroll
                    for (int kw = 0; kw < 3; ++kw) {
                        const int zl = u - kw;
                        if (zl < 0 || zl >= 5) continue;
                        const int z = zh * 5 + zl;
                        const int tap = kd * 9 + kh * 3 + kw;
                        #pragma unroll
                        for (int oh = 0; oh < 2; ++oh) {
                            const bf16x8 bf = *(const bf16x8*)&wt[
                                (size_t)(((z * 27 + tap) * 8 + cc * 4 + lk) * 32 + oh * 16 + lr) * 8];
                            acc[0][zl][oh] = __builtin_amdgcn_mfma_f32_16x16x32_bf16(a0, bf, acc[0][zl][oh], 0, 0, 0);
                            acc[1][zl][oh] = __builtin_amdgcn_mfma_f32_16x16x32_bf16(a1, bf, acc[1][zl][oh], 0, 0, 0);
                        }
                    }
                }
            }
        }
    }
    float* ob = out + (size_t)b * 15728640 + (size_t)d * 1280;
    #pragma unroll
    for (int m = 0; m < 2; ++m)
        #pragma unroll
        for (int zl = 0; zl < 5; ++zl)
            #pragma unroll
            for (int oh = 0; oh < 2; ++oh) {
                const int z = zh * 5 + zl;
                const int o = oh * 16 + lr;
                const int hl = (mp * 2 + m) * 16 + lk * 4;
                float* p = ob + (size_t)(64 + o) * 163840 + (h0 + hl) * 10 + z;
                #pragma unroll
                for (int r = 0; r < 4; ++r) {
                    float v = acc[m][zl][oh][r];
                    v = (v >= 0.f) ? v : 0.2f * v;
                    p[r * 10] = v;
                }
            }
}

// =============================== launch ===============================
extern "C" void kernel_launch(void* const* d_in, const int* in_sizes, int n_in,
                              void* d_out, int out_size, void* d_ws, size_t ws_size,
                              hipStream_t stream) {
    const float* x   = (const float*)d_in[0];
    const float* wts = (const float*)d_in[1];
    float* out = (float*)d_out;
    ushort_t* wt = (ushort_t*)d_ws;

    const size_t XT_OFF = 2u << 20;
    const size_t NEED = XT_OFF + (size_t)4 * XT_B * 2;

    prep_weights<<<2160, 256, 0, stream>>>(wts, wt);

    if (ws_size >= NEED) {
        ushort_t* xtp = (ushort_t*)((char*)d_ws + XT_OFF);
        zero_hpads<<<1024, 128, 0, stream>>>(xtp);
        repack_copy<<<4096, 256, 0, stream>>>(x, out, xtp);
        conv_v12<<<2048, 256, 0, stream>>>(xtp, wt, out);
    } else {
        copy_x<<<2048, 256, 0, stream>>>((const float4*)x, (float4*)out);
        conv_lc3d_v1<<<4 * 128 * 2, 256, 0, stream>>>(x, wt, out);
    }
}